// Round 15
// baseline (301.601 us; speedup 1.0000x reference)
//
#include <hip/hip_runtime.h>
#include <hip/hip_fp16.h>

#define N_NODES 100000
#define N_EDGES 3200000
#define IN_DIM 128
#define HID 64
#define NUM_GRAPHS 512
#define NUM_CLASSES 10

#define BSHIFT 9
#define BUCKET_W 512
#define NBUCKET ((N_NODES + BUCKET_W - 1) / BUCKET_W)  // 196
#define SRC_BITS 17
#define SRC_MASK ((1 << SRC_BITS) - 1)
#define NHBLK 256       // blocks in scatter
#define SEGSHIFT 14     // src segment = src >> 14 (16384 nodes = 2MB of hp)
#define NSEG 8
#define NREG (NSEG * NBUCKET)  // 1568 regions
#define REG_CAP 3584    // mean 2684, sigma~52 -> mean+17sigma

typedef _Float16 f16;
typedef f16 f16x8 __attribute__((ext_vector_type(8)));
typedef float f32x4 __attribute__((ext_vector_type(4)));

// ---------------- CSR build: (src-seg, dst-bucket) slack regions ------------

// Self-histogramming scatter into 1568 fixed regions. Region id encodes the
// src segment so bucket_fill can emit segment-sorted adjacency lists.
__global__ __launch_bounds__(256) void pair_scatter_kernel(const int* __restrict__ src,
                                                           const int* __restrict__ dst,
                                                           int* __restrict__ cursor,
                                                           unsigned* __restrict__ pair_buf) {
  __shared__ int h[NREG];  // 25 KB
  int tid = threadIdx.x;
  for (int i = tid; i < NREG; i += 256) h[i] = 0;
  __syncthreads();
  const int4* d4 = (const int4*)dst;
  const int4* s4 = (const int4*)src;
  const int nv = N_EDGES / 4 / NHBLK;  // 3125
  int v0 = blockIdx.x * nv, v1 = v0 + nv;
  for (int v = v0 + tid; v < v1; v += 256) {
    int4 d = d4[v];
    int4 s = s4[v];
    atomicAdd(&h[(s.x >> SEGSHIFT) * NBUCKET + (d.x >> BSHIFT)], 1);
    atomicAdd(&h[(s.y >> SEGSHIFT) * NBUCKET + (d.y >> BSHIFT)], 1);
    atomicAdd(&h[(s.z >> SEGSHIFT) * NBUCKET + (d.z >> BSHIFT)], 1);
    atomicAdd(&h[(s.w >> SEGSHIFT) * NBUCKET + (d.w >> BSHIFT)], 1);
  }
  __syncthreads();
  for (int i = tid; i < NREG; i += 256) {
    int c = h[i];
    if (c) h[i] = i * REG_CAP + atomicAdd(&cursor[i], c);
  }
  __syncthreads();
  for (int v = v0 + tid; v < v1; v += 256) {
    int4 d = d4[v];
    int4 s = s4[v];
    int r0 = (s.x >> SEGSHIFT) * NBUCKET + (d.x >> BSHIFT);
    int p0 = atomicAdd(&h[r0], 1);
    pair_buf[p0] = ((unsigned)(d.x & (BUCKET_W - 1)) << SRC_BITS) | (unsigned)s.x;
    int r1 = (s.y >> SEGSHIFT) * NBUCKET + (d.y >> BSHIFT);
    int p1 = atomicAdd(&h[r1], 1);
    pair_buf[p1] = ((unsigned)(d.y & (BUCKET_W - 1)) << SRC_BITS) | (unsigned)s.y;
    int r2 = (s.z >> SEGSHIFT) * NBUCKET + (d.z >> BSHIFT);
    int p2 = atomicAdd(&h[r2], 1);
    pair_buf[p2] = ((unsigned)(d.z & (BUCKET_W - 1)) << SRC_BITS) | (unsigned)s.z;
    int r3 = (s.w >> SEGSHIFT) * NBUCKET + (d.w >> BSHIFT);
    int p3 = atomicAdd(&h[r3], 1);
    pair_buf[p3] = ((unsigned)(d.w & (BUCKET_W - 1)) << SRC_BITS) | (unsigned)s.w;
  }
}

// One block per dst-bucket. Phase1: hist over all 8 segment sub-regions.
// Phase2: fill sub-regions IN SEGMENT ORDER (barrier between) so each
// node's adjacency list is sorted by src segment -> L2-resident gathers.
__global__ __launch_bounds__(512) void bucket_fill_kernel(const unsigned* __restrict__ pair_buf,
                                                          const int* __restrict__ cursor,
                                                          int* __restrict__ csr_src,
                                                          int* __restrict__ row_ptr,
                                                          float* __restrict__ dinv) {
  int k = blockIdx.x;
  int n0 = k << BSHIFT;
  int nn = min(BUCKET_W, N_NODES - n0);
  __shared__ int gb[NBUCKET + 1];
  __shared__ int hist[BUCKET_W];
  __shared__ int wsum[8];
  int tid = threadIdx.x;
  int lane = tid & 63, wid = tid >> 6;
  if (tid < 64) {  // scan of per-bucket totals -> global csr bases
    int carry = 0;
    for (int base = 0; base < NBUCKET; base += 64) {
      int i = base + tid;
      int v = 0;
      if (i < NBUCKET)
        for (int s = 0; s < NSEG; ++s) v += cursor[s * NBUCKET + i];
      int x = v;
#pragma unroll
      for (int off = 1; off < 64; off <<= 1) {
        int t = __shfl_up(x, off);
        if (tid >= off) x += t;
      }
      if (i < NBUCKET) gb[i] = carry + x - v;
      carry += __shfl(x, 63);
    }
    if (tid == 0) gb[NBUCKET] = carry;
  }
  hist[tid] = 0;
  __syncthreads();
  // phase 1: per-node histogram over all segment sub-regions
  for (int s = 0; s < NSEG; ++s) {
    int r = s * NBUCKET + k;
    int eb0 = r * REG_CAP;  // uint4-aligned
    int eb1 = eb0 + cursor[r];
    int a1 = eb1 & ~3;
    for (int e4 = (eb0 >> 2) + tid; e4 < (a1 >> 2); e4 += 512) {
      uint4 p = ((const uint4*)pair_buf)[e4];
      atomicAdd(&hist[p.x >> SRC_BITS], 1);
      atomicAdd(&hist[p.y >> SRC_BITS], 1);
      atomicAdd(&hist[p.z >> SRC_BITS], 1);
      atomicAdd(&hist[p.w >> SRC_BITS], 1);
    }
    for (int e = a1 + tid; e < eb1; e += 512)
      atomicAdd(&hist[pair_buf[e] >> SRC_BITS], 1);
  }
  __syncthreads();
  // scan 512 bins, thread t owns bin t
  int v = hist[tid];
  int x = v;
#pragma unroll
  for (int off = 1; off < 64; off <<= 1) {
    int t = __shfl_up(x, off);
    if (lane >= off) x += t;
  }
  if (lane == 63) wsum[wid] = x;
  __syncthreads();
  if (tid == 0) {
    int c = 0;
#pragma unroll
    for (int i = 0; i < 8; ++i) {
      int t = wsum[i];
      wsum[i] = c;
      c += t;
    }
  }
  __syncthreads();
  int base = gb[k] + x - v + wsum[wid];  // exclusive, global csr position
  if (tid < nn) {
    row_ptr[n0 + tid] = base;
    dinv[n0 + tid] = rsqrtf((float)(v + 1));
  }
  if (k == NBUCKET - 1 && tid == 0) row_ptr[N_NODES] = gb[NBUCKET];
  __syncthreads();
  hist[tid] = base;  // cursor
  __syncthreads();
  // phase 2: fill in segment order (barrier between segments)
  for (int s = 0; s < NSEG; ++s) {
    int r = s * NBUCKET + k;
    int eb0 = r * REG_CAP;
    int eb1 = eb0 + cursor[r];
    int a1 = eb1 & ~3;
    for (int e4 = (eb0 >> 2) + tid; e4 < (a1 >> 2); e4 += 512) {
      uint4 p = ((const uint4*)pair_buf)[e4];
      csr_src[atomicAdd(&hist[p.x >> SRC_BITS], 1)] = (int)(p.x & SRC_MASK);
      csr_src[atomicAdd(&hist[p.y >> SRC_BITS], 1)] = (int)(p.y & SRC_MASK);
      csr_src[atomicAdd(&hist[p.z >> SRC_BITS], 1)] = (int)(p.z & SRC_MASK);
      csr_src[atomicAdd(&hist[p.w >> SRC_BITS], 1)] = (int)(p.w & SRC_MASK);
    }
    for (int e = a1 + tid; e < eb1; e += 512) {
      unsigned p = pair_buf[e];
      csr_src[atomicAdd(&hist[p >> SRC_BITS], 1)] = (int)(p & SRC_MASK);
    }
    __syncthreads();  // enforce segment ordering within rows
  }
}

// ---------------- MFMA GEMM: hp[n][64] = f16((A[n][K]@W[K][64])*dinv[n]) ----
template <int K, bool SRC_F32>
__global__ __launch_bounds__(256) void mfma_gemm_kernel(const void* __restrict__ Asrc,
                                                        const float* __restrict__ W,
                                                        const float* __restrict__ dinv,
                                                        f16* __restrict__ hp, int n) {
  __shared__ f16 Ah[128][K + 8];
  __shared__ f16 Wt[64][K + 8];  // Wt[c][k] = W[k][c]
  int tid = threadIdx.x;
  int row0 = blockIdx.x * 128;
  for (int idx = tid; idx < K * 64; idx += 256) {
    int k = idx >> 6, c = idx & 63;
    Wt[c][k] = (f16)W[idx];
  }
  if (SRC_F32) {
    const float* A = (const float*)Asrc;
    for (int idx = tid * 4; idx < 128 * K; idx += 1024) {
      int r = idx / K, c = idx % K;
      float4 v = make_float4(0.f, 0.f, 0.f, 0.f);
      if (row0 + r < n) v = *(const float4*)&A[(size_t)(row0 + r) * K + c];
      Ah[r][c] = (f16)v.x;
      Ah[r][c + 1] = (f16)v.y;
      Ah[r][c + 2] = (f16)v.z;
      Ah[r][c + 3] = (f16)v.w;
    }
  } else {
    const f16* A = (const f16*)Asrc;
    for (int idx = tid * 8; idx < 128 * K; idx += 2048) {
      int r = idx / K, c = idx % K;
      uint4 z = make_uint4(0u, 0u, 0u, 0u);
      if (row0 + r < n) z = *(const uint4*)&A[(size_t)(row0 + r) * K + c];
      *(uint4*)&Ah[r][c] = z;
    }
  }
  __syncthreads();
  int w = tid >> 6, lane = tid & 63;
  int m0 = 32 * w;
  int kbase = (lane >> 4) * 8;
  int la = lane & 15;
  f32x4 acc[2][4] = {};
#pragma unroll
  for (int ks = 0; ks < K / 32; ++ks) {
    f16x8 a0 = *(const f16x8*)&Ah[m0 + la][32 * ks + kbase];
    f16x8 a1 = *(const f16x8*)&Ah[m0 + 16 + la][32 * ks + kbase];
#pragma unroll
    for (int t = 0; t < 4; ++t) {
      f16x8 b = *(const f16x8*)&Wt[16 * t + la][32 * ks + kbase];
      acc[0][t] = __builtin_amdgcn_mfma_f32_16x16x32_f16(a0, b, acc[0][t], 0, 0, 0);
      acc[1][t] = __builtin_amdgcn_mfma_f32_16x16x32_f16(a1, b, acc[1][t], 0, 0, 0);
    }
  }
#pragma unroll
  for (int mt = 0; mt < 2; ++mt) {
#pragma unroll
    for (int j = 0; j < 4; ++j) {
      int grow = row0 + m0 + 16 * mt + (lane >> 4) * 4 + j;
      if (grow < n) {
        float di = dinv[grow];
#pragma unroll
        for (int t = 0; t < 4; ++t)
          hp[(size_t)grow * 64 + 16 * t + la] = (f16)(acc[mt][t][j] * di);
      }
    }
  }
}

// ---------------- Aggregate: 2 nodes/wave, software-pipelined gathers -------
__global__ __launch_bounds__(256) void aggregate_kernel(
    const __half* __restrict__ hp, const int* __restrict__ row_ptr,
    const int* __restrict__ csr_src, const float* __restrict__ dinv,
    const float* __restrict__ bias, __half* __restrict__ out, int relu) {
  int node = blockIdx.x * 8 + (threadIdx.x >> 5);
  if (node >= N_NODES) return;
  int l = threadIdx.x & 31;  // dim-pair index
  const __half2* hp2 = (const __half2*)hp;
  int beg = row_ptr[node], end = row_ptr[node + 1];
  float2 acc = __half22float2(hp2[(unsigned)(node * 32 + l)]);  // self loop
  int e = beg;
  int rem = end - beg;
  if (rem >= 16) {
    int s_cur[16];
#pragma unroll
    for (int i = 0; i < 16; ++i) s_cur[i] = csr_src[e + i];
    while (rem >= 32) {
      int s_nxt[16];
#pragma unroll
      for (int i = 0; i < 16; ++i) s_nxt[i] = csr_src[e + 16 + i];
      float2 v_[16];
#pragma unroll
      for (int i = 0; i < 16; ++i)
        v_[i] = __half22float2(hp2[(unsigned)(s_cur[i] * 32 + l)]);
#pragma unroll
      for (int i = 0; i < 16; ++i) {
        acc.x += v_[i].x;
        acc.y += v_[i].y;
      }
#pragma unroll
      for (int i = 0; i < 16; ++i) s_cur[i] = s_nxt[i];
      e += 16;
      rem -= 16;
    }
    {  // drain the final full round
      float2 v_[16];
#pragma unroll
      for (int i = 0; i < 16; ++i)
        v_[i] = __half22float2(hp2[(unsigned)(s_cur[i] * 32 + l)]);
#pragma unroll
      for (int i = 0; i < 16; ++i) {
        acc.x += v_[i].x;
        acc.y += v_[i].y;
      }
      e += 16;
      rem -= 16;
    }
  }
  if (rem) {  // masked 16-round; clamped dup indices are L1-hot
    int last = end - 1;
    int s_[16];
#pragma unroll
    for (int i = 0; i < 16; ++i) s_[i] = csr_src[min(e + i, last)];
    float2 v_[16];
#pragma unroll
    for (int i = 0; i < 16; ++i)
      v_[i] = __half22float2(hp2[(unsigned)(s_[i] * 32 + l)]);
#pragma unroll
    for (int i = 0; i < 16; ++i) {
      if (i < rem) {
        acc.x += v_[i].x;
        acc.y += v_[i].y;
      }
    }
  }
  float di = dinv[node];
  float2 b = *(const float2*)&bias[2 * l];
  float rx = acc.x * di + b.x;
  float ry = acc.y * di + b.y;
  if (relu) {
    rx = fmaxf(rx, 0.0f);
    ry = fmaxf(ry, 0.0f);
  }
  ((__half2*)out)[(unsigned)(node * 32 + l)] = __floats2half2_rn(rx, ry);
}

// ---------------- Fused mean-pool + FC (wave per graph, no atomics) ---------
__global__ __launch_bounds__(256) void pool_fc_kernel(const __half* __restrict__ h,
                                                      const int* __restrict__ batch,
                                                      const float* __restrict__ Wfc,
                                                      const float* __restrict__ bfc,
                                                      float* __restrict__ out) {
  int g = blockIdx.x * 4 + (threadIdx.x >> 6);
  if (g >= NUM_GRAPHS) return;
  int lane = threadIdx.x & 63;
  int lo = 0, hi = N_NODES;
  while (lo < hi) {
    int m = (lo + hi) >> 1;
    if (batch[m] < g) lo = m + 1; else hi = m;
  }
  int n0 = lo;
  hi = N_NODES;
  while (lo < hi) {
    int m = (lo + hi) >> 1;
    if (batch[m] < g + 1) lo = m + 1; else hi = m;
  }
  int n1 = lo;
  float acc = 0.f, acc2 = 0.f;
  int nn = n0;
  for (; nn + 8 <= n1; nn += 8) {
    float a0 = __half2float(h[(size_t)(nn + 0) * HID + lane]);
    float a1 = __half2float(h[(size_t)(nn + 1) * HID + lane]);
    float a2 = __half2float(h[(size_t)(nn + 2) * HID + lane]);
    float a3 = __half2float(h[(size_t)(nn + 3) * HID + lane]);
    float a4 = __half2float(h[(size_t)(nn + 4) * HID + lane]);
    float a5 = __half2float(h[(size_t)(nn + 5) * HID + lane]);
    float a6 = __half2float(h[(size_t)(nn + 6) * HID + lane]);
    float a7 = __half2float(h[(size_t)(nn + 7) * HID + lane]);
    acc += a0 + a1 + a2 + a3;
    acc2 += a4 + a5 + a6 + a7;
  }
  for (; nn < n1; ++nn) acc += __half2float(h[(size_t)nn * HID + lane]);
  acc += acc2;
  float s = acc / fmaxf((float)(n1 - n0), 1.0f);
#pragma unroll
  for (int o = 0; o < NUM_CLASSES; ++o) {
    float p = s * Wfc[lane * NUM_CLASSES + o];
#pragma unroll
    for (int m = 32; m >= 1; m >>= 1) p += __shfl_xor(p, m);
    if (lane == o) out[(size_t)g * NUM_CLASSES + o] = p + bfc[o];
  }
}

// ---------------- launch -----------------------------------------------------
extern "C" void kernel_launch(void* const* d_in, const int* in_sizes, int n_in,
                              void* d_out, int out_size, void* d_ws, size_t ws_size,
                              hipStream_t stream) {
  const float* x = (const float*)d_in[0];
  const int* edge_index = (const int*)d_in[1];
  const int* batch = (const int*)d_in[2];
  const float* W1 = (const float*)d_in[3];
  const float* b1 = (const float*)d_in[4];
  const float* W2 = (const float*)d_in[5];
  const float* b2 = (const float*)d_in[6];
  const float* W3 = (const float*)d_in[7];
  const float* b3 = (const float*)d_in[8];
  const float* Wfc = (const float*)d_in[9];
  const float* bfc = (const float*)d_in[10];
  float* out = (float*)d_out;

  const int* src = edge_index;
  const int* dst = edge_index + N_EDGES;

  // workspace layout
  char* w = (char*)d_ws;
  __half* h16 = (__half*)w;                        // N*64 f16 (aggregate out / GEMM A)
  __half* hp = h16 + (size_t)N_NODES * HID;        // N*64 f16 (GEMM out, gather buf)
  float* dinv = (float*)(hp + (size_t)N_NODES * HID);  // N
  int* row_ptr = (int*)(dinv + N_NODES);           // N+1
  int* csr_src = row_ptr + (N_NODES + 1);          // E
  int* cursor = csr_src + N_EDGES;                 // NREG
  // pair_buf aliases h16+hp (25.6MB window, needs 22.5MB); dead before GEMM1.
  unsigned* pair_buf = (unsigned*)h16;

  hipMemsetAsync(cursor, 0, NREG * sizeof(int), stream);

  // CSR build
  pair_scatter_kernel<<<NHBLK, 256, 0, stream>>>(src, dst, cursor, pair_buf);
  bucket_fill_kernel<<<NBUCKET, 512, 0, stream>>>(pair_buf, cursor, csr_src,
                                                  row_ptr, dinv);

  const int ggrid = (N_NODES + 127) / 128;
  const int agrid = (N_NODES + 7) / 8;

  // layer 1
  mfma_gemm_kernel<IN_DIM, true><<<ggrid, 256, 0, stream>>>(x, W1, dinv, (f16*)hp,
                                                            N_NODES);
  aggregate_kernel<<<agrid, 256, 0, stream>>>(hp, row_ptr, csr_src, dinv, b1, h16, 1);
  // layer 2
  mfma_gemm_kernel<HID, false><<<ggrid, 256, 0, stream>>>(h16, W2, dinv, (f16*)hp,
                                                          N_NODES);
  aggregate_kernel<<<agrid, 256, 0, stream>>>(hp, row_ptr, csr_src, dinv, b2, h16, 1);
  // layer 3
  mfma_gemm_kernel<HID, false><<<ggrid, 256, 0, stream>>>(h16, W3, dinv, (f16*)hp,
                                                          N_NODES);
  aggregate_kernel<<<agrid, 256, 0, stream>>>(hp, row_ptr, csr_src, dinv, b3, h16, 0);

  // fused pool + fc
  pool_fc_kernel<<<(NUM_GRAPHS + 3) / 4, 256, 0, stream>>>(h16, batch, Wfc, bfc, out);
}

// Round 16
// 284.413 us; speedup vs baseline: 1.0604x; 1.0604x over previous
//
#include <hip/hip_runtime.h>
#include <hip/hip_fp16.h>

#define N_NODES 100000
#define N_EDGES 3200000
#define IN_DIM 128
#define HID 64
#define NUM_GRAPHS 512
#define NUM_CLASSES 10

#define BSHIFT 9
#define BUCKET_W 512
#define NBUCKET ((N_NODES + BUCKET_W - 1) / BUCKET_W)  // 196
#define SRC_BITS 17
#define SRC_MASK ((1 << SRC_BITS) - 1)
#define NHBLK 256       // blocks in scatter
#define PAIR_CAP 18432  // slack region per bucket (mean 16384, sigma~128)

typedef _Float16 f16;
typedef f16 f16x8 __attribute__((ext_vector_type(8)));
typedef float f32x4 __attribute__((ext_vector_type(4)));

// ---------------- CSR build (slack-region, 2 kernels) -----------------------

// Self-histogramming scatter: pass1 hist own chunk (dst), reserve runs via
// global cursor atomics into FIXED per-bucket slack regions; pass2 re-read
// (L2-hot) and scatter.
__global__ __launch_bounds__(256) void pair_scatter_kernel(const int* __restrict__ src,
                                                           const int* __restrict__ dst,
                                                           int* __restrict__ cursor,
                                                           unsigned* __restrict__ pair_buf) {
  __shared__ int h[NBUCKET];
  int tid = threadIdx.x;
  for (int i = tid; i < NBUCKET; i += 256) h[i] = 0;
  __syncthreads();
  const int4* d4 = (const int4*)dst;
  const int4* s4 = (const int4*)src;
  const int nv = N_EDGES / 4 / NHBLK;  // 3125
  int v0 = blockIdx.x * nv, v1 = v0 + nv;
  for (int v = v0 + tid; v < v1; v += 256) {
    int4 d = d4[v];
    atomicAdd(&h[d.x >> BSHIFT], 1);
    atomicAdd(&h[d.y >> BSHIFT], 1);
    atomicAdd(&h[d.z >> BSHIFT], 1);
    atomicAdd(&h[d.w >> BSHIFT], 1);
  }
  __syncthreads();
  for (int i = tid; i < NBUCKET; i += 256) {
    int c = h[i];
    if (c) h[i] = i * PAIR_CAP + atomicAdd(&cursor[i], c);
  }
  __syncthreads();
  for (int v = v0 + tid; v < v1; v += 256) {
    int4 d = d4[v];
    int4 s = s4[v];
    int p0 = atomicAdd(&h[d.x >> BSHIFT], 1);
    pair_buf[p0] = ((unsigned)(d.x & (BUCKET_W - 1)) << SRC_BITS) | (unsigned)s.x;
    int p1 = atomicAdd(&h[d.y >> BSHIFT], 1);
    pair_buf[p1] = ((unsigned)(d.y & (BUCKET_W - 1)) << SRC_BITS) | (unsigned)s.y;
    int p2 = atomicAdd(&h[d.z >> BSHIFT], 1);
    pair_buf[p2] = ((unsigned)(d.z & (BUCKET_W - 1)) << SRC_BITS) | (unsigned)s.z;
    int p3 = atomicAdd(&h[d.w >> BSHIFT], 1);
    pair_buf[p3] = ((unsigned)(d.w & (BUCKET_W - 1)) << SRC_BITS) | (unsigned)s.w;
  }
}

// One block per bucket. Derives global CSR bases by scanning final counts
// (cursor[], L2-hot); then per-node hist -> row_ptr/dinv -> fill.
__global__ __launch_bounds__(512) void bucket_fill_kernel(const unsigned* __restrict__ pair_buf,
                                                          const int* __restrict__ cursor,
                                                          int* __restrict__ csr_src,
                                                          int* __restrict__ row_ptr,
                                                          float* __restrict__ dinv) {
  int k = blockIdx.x;
  int n0 = k << BSHIFT;
  int nn = min(BUCKET_W, N_NODES - n0);
  __shared__ int gb[NBUCKET + 1];
  __shared__ int hist[BUCKET_W];
  __shared__ int wsum[8];
  int tid = threadIdx.x;
  int lane = tid & 63, wid = tid >> 6;
  if (tid < 64) {  // scan of bucket counts -> global csr bases
    int carry = 0;
    for (int base = 0; base < NBUCKET; base += 64) {
      int i = base + tid;
      int v = (i < NBUCKET) ? cursor[i] : 0;
      int x = v;
#pragma unroll
      for (int off = 1; off < 64; off <<= 1) {
        int t = __shfl_up(x, off);
        if (tid >= off) x += t;
      }
      if (i < NBUCKET) gb[i] = carry + x - v;
      carry += __shfl(x, 63);
    }
    if (tid == 0) gb[NBUCKET] = carry;
  }
  hist[tid] = 0;
  __syncthreads();
  int eb0 = k * PAIR_CAP;             // uint4-aligned
  int eb1 = eb0 + cursor[k];
  int a1 = eb1 & ~3;
  int csr0 = gb[k];
  // pass 1: histogram
  for (int e4 = (eb0 >> 2) + tid; e4 < (a1 >> 2); e4 += 512) {
    uint4 p = ((const uint4*)pair_buf)[e4];
    atomicAdd(&hist[p.x >> SRC_BITS], 1);
    atomicAdd(&hist[p.y >> SRC_BITS], 1);
    atomicAdd(&hist[p.z >> SRC_BITS], 1);
    atomicAdd(&hist[p.w >> SRC_BITS], 1);
  }
  for (int e = a1 + tid; e < eb1; e += 512)
    atomicAdd(&hist[pair_buf[e] >> SRC_BITS], 1);
  __syncthreads();
  // scan 512 bins, thread t owns bin t
  int v = hist[tid];
  int x = v;
#pragma unroll
  for (int off = 1; off < 64; off <<= 1) {
    int t = __shfl_up(x, off);
    if (lane >= off) x += t;
  }
  if (lane == 63) wsum[wid] = x;
  __syncthreads();
  if (tid == 0) {
    int c = 0;
#pragma unroll
    for (int i = 0; i < 8; ++i) {
      int t = wsum[i];
      wsum[i] = c;
      c += t;
    }
  }
  __syncthreads();
  int base = csr0 + x - v + wsum[wid];  // exclusive, global csr position
  if (tid < nn) {
    row_ptr[n0 + tid] = base;
    dinv[n0 + tid] = rsqrtf((float)(v + 1));
  }
  if (k == NBUCKET - 1 && tid == 0) row_ptr[N_NODES] = gb[NBUCKET];
  __syncthreads();
  hist[tid] = base;  // cursor
  __syncthreads();
  // pass 2: fill
  for (int e4 = (eb0 >> 2) + tid; e4 < (a1 >> 2); e4 += 512) {
    uint4 p = ((const uint4*)pair_buf)[e4];
    csr_src[atomicAdd(&hist[p.x >> SRC_BITS], 1)] = (int)(p.x & SRC_MASK);
    csr_src[atomicAdd(&hist[p.y >> SRC_BITS], 1)] = (int)(p.y & SRC_MASK);
    csr_src[atomicAdd(&hist[p.z >> SRC_BITS], 1)] = (int)(p.z & SRC_MASK);
    csr_src[atomicAdd(&hist[p.w >> SRC_BITS], 1)] = (int)(p.w & SRC_MASK);
  }
  for (int e = a1 + tid; e < eb1; e += 512) {
    unsigned p = pair_buf[e];
    csr_src[atomicAdd(&hist[p >> SRC_BITS], 1)] = (int)(p & SRC_MASK);
  }
}

// ---------------- MFMA GEMM: hp[n][64] = f16((A[n][K]@W[K][64])*dinv[n]) ----
template <int K, bool SRC_F32>
__global__ __launch_bounds__(256) void mfma_gemm_kernel(const void* __restrict__ Asrc,
                                                        const float* __restrict__ W,
                                                        const float* __restrict__ dinv,
                                                        f16* __restrict__ hp, int n) {
  __shared__ f16 Ah[128][K + 8];
  __shared__ f16 Wt[64][K + 8];  // Wt[c][k] = W[k][c]
  int tid = threadIdx.x;
  int row0 = blockIdx.x * 128;
  for (int idx = tid; idx < K * 64; idx += 256) {
    int k = idx >> 6, c = idx & 63;
    Wt[c][k] = (f16)W[idx];
  }
  if (SRC_F32) {
    const float* A = (const float*)Asrc;
    for (int idx = tid * 4; idx < 128 * K; idx += 1024) {
      int r = idx / K, c = idx % K;
      float4 v = make_float4(0.f, 0.f, 0.f, 0.f);
      if (row0 + r < n) v = *(const float4*)&A[(size_t)(row0 + r) * K + c];
      Ah[r][c] = (f16)v.x;
      Ah[r][c + 1] = (f16)v.y;
      Ah[r][c + 2] = (f16)v.z;
      Ah[r][c + 3] = (f16)v.w;
    }
  } else {
    const f16* A = (const f16*)Asrc;
    for (int idx = tid * 8; idx < 128 * K; idx += 2048) {
      int r = idx / K, c = idx % K;
      uint4 z = make_uint4(0u, 0u, 0u, 0u);
      if (row0 + r < n) z = *(const uint4*)&A[(size_t)(row0 + r) * K + c];
      *(uint4*)&Ah[r][c] = z;
    }
  }
  __syncthreads();
  int w = tid >> 6, lane = tid & 63;
  int m0 = 32 * w;
  int kbase = (lane >> 4) * 8;
  int la = lane & 15;
  f32x4 acc[2][4] = {};
#pragma unroll
  for (int ks = 0; ks < K / 32; ++ks) {
    f16x8 a0 = *(const f16x8*)&Ah[m0 + la][32 * ks + kbase];
    f16x8 a1 = *(const f16x8*)&Ah[m0 + 16 + la][32 * ks + kbase];
#pragma unroll
    for (int t = 0; t < 4; ++t) {
      f16x8 b = *(const f16x8*)&Wt[16 * t + la][32 * ks + kbase];
      acc[0][t] = __builtin_amdgcn_mfma_f32_16x16x32_f16(a0, b, acc[0][t], 0, 0, 0);
      acc[1][t] = __builtin_amdgcn_mfma_f32_16x16x32_f16(a1, b, acc[1][t], 0, 0, 0);
    }
  }
#pragma unroll
  for (int mt = 0; mt < 2; ++mt) {
#pragma unroll
    for (int j = 0; j < 4; ++j) {
      int grow = row0 + m0 + 16 * mt + (lane >> 4) * 4 + j;
      if (grow < n) {
        float di = dinv[grow];
#pragma unroll
        for (int t = 0; t < 4; ++t)
          hp[(size_t)grow * 64 + 16 * t + la] = (f16)(acc[mt][t][j] * di);
      }
    }
  }
}

// ---------------- Aggregate: 2 nodes/wave, software-pipelined gathers -------
__global__ __launch_bounds__(256) void aggregate_kernel(
    const __half* __restrict__ hp, const int* __restrict__ row_ptr,
    const int* __restrict__ csr_src, const float* __restrict__ dinv,
    const float* __restrict__ bias, __half* __restrict__ out, int relu) {
  int node = blockIdx.x * 8 + (threadIdx.x >> 5);
  if (node >= N_NODES) return;
  int l = threadIdx.x & 31;  // dim-pair index
  const __half2* hp2 = (const __half2*)hp;
  int beg = row_ptr[node], end = row_ptr[node + 1];
  float2 acc = __half22float2(hp2[(unsigned)(node * 32 + l)]);  // self loop
  int e = beg;
  int rem = end - beg;
  if (rem >= 16) {
    int s_cur[16];
#pragma unroll
    for (int i = 0; i < 16; ++i) s_cur[i] = csr_src[e + i];
    while (rem >= 32) {
      int s_nxt[16];
#pragma unroll
      for (int i = 0; i < 16; ++i) s_nxt[i] = csr_src[e + 16 + i];
      float2 v_[16];
#pragma unroll
      for (int i = 0; i < 16; ++i)
        v_[i] = __half22float2(hp2[(unsigned)(s_cur[i] * 32 + l)]);
#pragma unroll
      for (int i = 0; i < 16; ++i) {
        acc.x += v_[i].x;
        acc.y += v_[i].y;
      }
#pragma unroll
      for (int i = 0; i < 16; ++i) s_cur[i] = s_nxt[i];
      e += 16;
      rem -= 16;
    }
    {  // drain the final full round
      float2 v_[16];
#pragma unroll
      for (int i = 0; i < 16; ++i)
        v_[i] = __half22float2(hp2[(unsigned)(s_cur[i] * 32 + l)]);
#pragma unroll
      for (int i = 0; i < 16; ++i) {
        acc.x += v_[i].x;
        acc.y += v_[i].y;
      }
      e += 16;
      rem -= 16;
    }
  }
  if (rem) {  // masked 16-round; clamped dup indices are L1-hot
    int last = end - 1;
    int s_[16];
#pragma unroll
    for (int i = 0; i < 16; ++i) s_[i] = csr_src[min(e + i, last)];
    float2 v_[16];
#pragma unroll
    for (int i = 0; i < 16; ++i)
      v_[i] = __half22float2(hp2[(unsigned)(s_[i] * 32 + l)]);
#pragma unroll
    for (int i = 0; i < 16; ++i) {
      if (i < rem) {
        acc.x += v_[i].x;
        acc.y += v_[i].y;
      }
    }
  }
  float di = dinv[node];
  float2 b = *(const float2*)&bias[2 * l];
  float rx = acc.x * di + b.x;
  float ry = acc.y * di + b.y;
  if (relu) {
    rx = fmaxf(rx, 0.0f);
    ry = fmaxf(ry, 0.0f);
  }
  ((__half2*)out)[(unsigned)(node * 32 + l)] = __floats2half2_rn(rx, ry);
}

// ---------------- Fused mean-pool + FC (wave per graph, no atomics) ---------
__global__ __launch_bounds__(256) void pool_fc_kernel(const __half* __restrict__ h,
                                                      const int* __restrict__ batch,
                                                      const float* __restrict__ Wfc,
                                                      const float* __restrict__ bfc,
                                                      float* __restrict__ out) {
  int g = blockIdx.x * 4 + (threadIdx.x >> 6);
  if (g >= NUM_GRAPHS) return;
  int lane = threadIdx.x & 63;
  int lo = 0, hi = N_NODES;
  while (lo < hi) {
    int m = (lo + hi) >> 1;
    if (batch[m] < g) lo = m + 1; else hi = m;
  }
  int n0 = lo;
  hi = N_NODES;
  while (lo < hi) {
    int m = (lo + hi) >> 1;
    if (batch[m] < g + 1) lo = m + 1; else hi = m;
  }
  int n1 = lo;
  float acc = 0.f, acc2 = 0.f;
  int nn = n0;
  for (; nn + 8 <= n1; nn += 8) {
    float a0 = __half2float(h[(size_t)(nn + 0) * HID + lane]);
    float a1 = __half2float(h[(size_t)(nn + 1) * HID + lane]);
    float a2 = __half2float(h[(size_t)(nn + 2) * HID + lane]);
    float a3 = __half2float(h[(size_t)(nn + 3) * HID + lane]);
    float a4 = __half2float(h[(size_t)(nn + 4) * HID + lane]);
    float a5 = __half2float(h[(size_t)(nn + 5) * HID + lane]);
    float a6 = __half2float(h[(size_t)(nn + 6) * HID + lane]);
    float a7 = __half2float(h[(size_t)(nn + 7) * HID + lane]);
    acc += a0 + a1 + a2 + a3;
    acc2 += a4 + a5 + a6 + a7;
  }
  for (; nn < n1; ++nn) acc += __half2float(h[(size_t)nn * HID + lane]);
  acc += acc2;
  float s = acc / fmaxf((float)(n1 - n0), 1.0f);
#pragma unroll
  for (int o = 0; o < NUM_CLASSES; ++o) {
    float p = s * Wfc[lane * NUM_CLASSES + o];
#pragma unroll
    for (int m = 32; m >= 1; m >>= 1) p += __shfl_xor(p, m);
    if (lane == o) out[(size_t)g * NUM_CLASSES + o] = p + bfc[o];
  }
}

// ---------------- launch -----------------------------------------------------
extern "C" void kernel_launch(void* const* d_in, const int* in_sizes, int n_in,
                              void* d_out, int out_size, void* d_ws, size_t ws_size,
                              hipStream_t stream) {
  const float* x = (const float*)d_in[0];
  const int* edge_index = (const int*)d_in[1];
  const int* batch = (const int*)d_in[2];
  const float* W1 = (const float*)d_in[3];
  const float* b1 = (const float*)d_in[4];
  const float* W2 = (const float*)d_in[5];
  const float* b2 = (const float*)d_in[6];
  const float* W3 = (const float*)d_in[7];
  const float* b3 = (const float*)d_in[8];
  const float* Wfc = (const float*)d_in[9];
  const float* bfc = (const float*)d_in[10];
  float* out = (float*)d_out;

  const int* src = edge_index;
  const int* dst = edge_index + N_EDGES;

  // workspace layout
  char* w = (char*)d_ws;
  __half* h16 = (__half*)w;                        // N*64 f16 (aggregate out / GEMM A)
  __half* hp = h16 + (size_t)N_NODES * HID;        // N*64 f16 (GEMM out, gather buf)
  float* dinv = (float*)(hp + (size_t)N_NODES * HID);  // N
  int* row_ptr = (int*)(dinv + N_NODES);           // N+1
  int* csr_src = row_ptr + (N_NODES + 1);          // E
  int* cursor = csr_src + N_EDGES;                 // NBUCKET
  // pair_buf aliases h16+hp (25.6MB window, needs 14.45MB); dead before GEMM1.
  unsigned* pair_buf = (unsigned*)h16;

  hipMemsetAsync(cursor, 0, NBUCKET * sizeof(int), stream);

  // CSR build
  pair_scatter_kernel<<<NHBLK, 256, 0, stream>>>(src, dst, cursor, pair_buf);
  bucket_fill_kernel<<<NBUCKET, 512, 0, stream>>>(pair_buf, cursor, csr_src,
                                                  row_ptr, dinv);

  const int ggrid = (N_NODES + 127) / 128;
  const int agrid = (N_NODES + 7) / 8;

  // layer 1
  mfma_gemm_kernel<IN_DIM, true><<<ggrid, 256, 0, stream>>>(x, W1, dinv, (f16*)hp,
                                                            N_NODES);
  aggregate_kernel<<<agrid, 256, 0, stream>>>(hp, row_ptr, csr_src, dinv, b1, h16, 1);
  // layer 2
  mfma_gemm_kernel<HID, false><<<ggrid, 256, 0, stream>>>(h16, W2, dinv, (f16*)hp,
                                                          N_NODES);
  aggregate_kernel<<<agrid, 256, 0, stream>>>(hp, row_ptr, csr_src, dinv, b2, h16, 1);
  // layer 3
  mfma_gemm_kernel<HID, false><<<ggrid, 256, 0, stream>>>(h16, W3, dinv, (f16*)hp,
                                                          N_NODES);
  aggregate_kernel<<<agrid, 256, 0, stream>>>(hp, row_ptr, csr_src, dinv, b3, h16, 0);

  // fused pool + fc
  pool_fc_kernel<<<(NUM_GRAPHS + 3) / 4, 256, 0, stream>>>(h16, batch, Wfc, bfc, out);
}